// Round 10
// baseline (643.700 us; speedup 1.0000x reference)
//
#include <hip/hip_runtime.h>

#define N_NODES 100000
#define N_EDGES 1600000
#define IN_F 32
#define HID_F 64
#define OUT_F 16
#define BSIZE 512                    // nodes per bucket (bucket = dst >> 9)
#define NBKT 256                     // scan width in bucket_kernel (196 used)
#define CAP 10240                    // edge capacity per bucket slab (mean 8192, >20 sd margin)
#define CHUNK 4096                   // edges per block in bucket-sort pass (391 blocks)
#define NBUCK ((N_NODES + BSIZE - 1) / BSIZE)   // 196
#define NCHUNK ((N_EDGES + CHUNK - 1) / CHUNK)  // 391
#define APITCH 68                    // padded pitch for transposed A / h1 tiles
#define AP1 33                       // agg1 acc pitch: bank=(d+j)%32, atomic-conflict-free
#define AP2 17                       // agg2 acc pitch: gcd(17,32)=1, spread by dst

using f2v = __attribute__((ext_vector_type(2))) float;

// float -> bf16 (round-to-nearest-even), returned in low 16 bits
__device__ __forceinline__ unsigned f2bf(float f) {
  unsigned u = __float_as_uint(f);
  return (u + 0x7FFFu + ((u >> 16) & 1u)) >> 16;
}

// decode uint4 of 16 fp8-e4m3 and atomicAdd into LDS floats ap[off..off+15]
#define ADDQL(ap, Q, off) do { f2v p_; \
  p_ = __builtin_amdgcn_cvt_pk_f32_fp8((int)(Q).x, false); atomicAdd((ap)+(off)+0,  p_[0]); atomicAdd((ap)+(off)+1,  p_[1]); \
  p_ = __builtin_amdgcn_cvt_pk_f32_fp8((int)(Q).x, true);  atomicAdd((ap)+(off)+2,  p_[0]); atomicAdd((ap)+(off)+3,  p_[1]); \
  p_ = __builtin_amdgcn_cvt_pk_f32_fp8((int)(Q).y, false); atomicAdd((ap)+(off)+4,  p_[0]); atomicAdd((ap)+(off)+5,  p_[1]); \
  p_ = __builtin_amdgcn_cvt_pk_f32_fp8((int)(Q).y, true);  atomicAdd((ap)+(off)+6,  p_[0]); atomicAdd((ap)+(off)+7,  p_[1]); \
  p_ = __builtin_amdgcn_cvt_pk_f32_fp8((int)(Q).z, false); atomicAdd((ap)+(off)+8,  p_[0]); atomicAdd((ap)+(off)+9,  p_[1]); \
  p_ = __builtin_amdgcn_cvt_pk_f32_fp8((int)(Q).z, true);  atomicAdd((ap)+(off)+10, p_[0]); atomicAdd((ap)+(off)+11, p_[1]); \
  p_ = __builtin_amdgcn_cvt_pk_f32_fp8((int)(Q).w, false); atomicAdd((ap)+(off)+12, p_[0]); atomicAdd((ap)+(off)+13, p_[1]); \
  p_ = __builtin_amdgcn_cvt_pk_f32_fp8((int)(Q).w, true);  atomicAdd((ap)+(off)+14, p_[0]); atomicAdd((ap)+(off)+15, p_[1]); \
} while (0)

// ---------------- slab cursor init ----------------
__global__ __launch_bounds__(NBKT) void cursor_init_kernel(int* __restrict__ cursor) {
  cursor[threadIdx.x] = threadIdx.x * CAP;
}

// ---- one-pass LDS-staged bucket sort; packed (src<<9)|dstLocal. Wave-shfl scan.
//      391 blocks x 512 thr. Absorbs feat->fp8 conversion. (byte-identical to R9) ----
__global__ __launch_bounds__(512) void bucket_kernel(
    const int* __restrict__ src, const int* __restrict__ dst,
    const float4* __restrict__ featin, uint4* __restrict__ featfp8,
    int* __restrict__ cursor, unsigned* __restrict__ sorted) {
  __shared__ unsigned stage[CHUNK];        // 16 KB
  __shared__ unsigned char sbkt[CHUNK];    // 4 KB
  __shared__ int lcnt[NBKT], lscan[NBKT], goff[NBKT];
  __shared__ int wsum[4];
  int t = threadIdx.x;

  // ---- absorbed conversion: feat -> fp8 e4m3 (16 floats per thread, independent work) ----
  {
    int gtid = blockIdx.x * 512 + t;       // 391*512 = 200192 >= 200000
    if (gtid < N_NODES * IN_F / 16) {
      float4 a = featin[4 * gtid], bb = featin[4 * gtid + 1];
      float4 c4 = featin[4 * gtid + 2], d = featin[4 * gtid + 3];
      uint4 r;
      int w;
      w = __builtin_amdgcn_cvt_pk_fp8_f32(a.x, a.y, 0, false);
      w = __builtin_amdgcn_cvt_pk_fp8_f32(a.z, a.w, w, true);
      r.x = (unsigned)w;
      w = __builtin_amdgcn_cvt_pk_fp8_f32(bb.x, bb.y, 0, false);
      w = __builtin_amdgcn_cvt_pk_fp8_f32(bb.z, bb.w, w, true);
      r.y = (unsigned)w;
      w = __builtin_amdgcn_cvt_pk_fp8_f32(c4.x, c4.y, 0, false);
      w = __builtin_amdgcn_cvt_pk_fp8_f32(c4.z, c4.w, w, true);
      r.z = (unsigned)w;
      w = __builtin_amdgcn_cvt_pk_fp8_f32(d.x, d.y, 0, false);
      w = __builtin_amdgcn_cvt_pk_fp8_f32(d.z, d.w, w, true);
      r.w = (unsigned)w;
      featfp8[gtid] = r;
    }
  }

  if (t < NBKT) lcnt[t] = 0;
  __syncthreads();

  int base = blockIdx.x * CHUNK;
  unsigned mypk[CHUNK / 512];
  int myb[CHUNK / 512], myrank[CHUNK / 512];
#pragma unroll
  for (int i = 0; i < CHUNK / 512; ++i) {
    int e = base + t + 512 * i;
    if (e < N_EDGES) {
      unsigned s = (unsigned)src[e], d = (unsigned)dst[e];
      myb[i] = (int)(d >> 9);
      mypk[i] = (s << 9) | (d & 511u);
      myrank[i] = atomicAdd(&lcnt[myb[i]], 1);
    } else {
      myb[i] = -1;
    }
  }
  __syncthreads();

  // ---- inclusive scan of lcnt[0..255] via wave shfl (threads 0..255 = waves 0..3) ----
  int x = 0;
  if (t < NBKT) {
    x = lcnt[t];
#pragma unroll
    for (int off = 1; off < 64; off <<= 1) {
      int y = __shfl_up(x, off);
      if ((t & 63) >= off) x += y;
    }
    if ((t & 63) == 63) wsum[t >> 6] = x;
  }
  __syncthreads();
  if (t < NBKT) {
    int w = t >> 6, add = 0;
    if (w > 0) add += wsum[0];
    if (w > 1) add += wsum[1];
    if (w > 2) add += wsum[2];
    int incl = x + add;
    lscan[t] = incl;
    int gb = lcnt[t] ? atomicAdd(&cursor[t], lcnt[t]) : 0;
    goff[t] = gb - incl + lcnt[t];   // addr = goff[b] + slot
  }
  __syncthreads();

#pragma unroll
  for (int i = 0; i < CHUNK / 512; ++i) {
    if (myb[i] >= 0) {
      int slot = (lscan[myb[i]] - lcnt[myb[i]]) + myrank[i];
      stage[slot] = mypk[i];
      sbkt[slot] = (unsigned char)myb[i];
    }
  }
  __syncthreads();
  int nvalid = min(CHUNK, N_EDGES - base);
  for (int i = t; i < nvalid; i += 512) {
    int b = (int)sbkt[i];
    sorted[goff[b] + i] = stage[i];
  }
}

// ---- layer-1 aggregation, EDGE-PARALLEL: one block per bucket streams its slab
//      coalesced; per edge: decode featfp8[src] (L2) + 32 LDS f32 atomics into the
//      padded per-node accumulator. No dependent chains, no col arena. Writes
//      per-node mean as bf16 (meanb) for dense consumption by l1g. ----
__global__ __launch_bounds__(1024) void agg1_kernel(
    const unsigned* __restrict__ sorted, const int* __restrict__ cursor,
    const uint4* __restrict__ featfp8, uint4* __restrict__ meanb) {
  __shared__ float acc[BSIZE * AP1];   // 512*33*4 = 67.6 KB
  __shared__ int dcnt[BSIZE];
  int t = threadIdx.x;
  int b = blockIdx.x;
  for (int i = t; i < BSIZE * AP1; i += 1024) acc[i] = 0.0f;
  if (t < BSIZE) dcnt[t] = 0;
  __syncthreads();

  int cbase = b * CAP;
  int ne = cursor[b] - cbase;
  for (int i = t; i < ne; i += 1024) {
    unsigned p = sorted[cbase + i];       // coalesced
    int d = (int)(p & (BSIZE - 1));
    int sv = (int)(p >> 9);
    uint4 q0 = featfp8[sv * 2];
    uint4 q1 = featfp8[sv * 2 + 1];
    atomicAdd(&dcnt[d], 1);
    float* ap = &acc[d * AP1];            // bank = (d+j)%32: spread by random d
    ADDQL(ap, q0, 0);
    ADDQL(ap, q1, 16);
  }
  __syncthreads();

  // ---- epilogue: 2 threads/node, mean -> bf16, dense coalesced write ----
  int n = t >> 1, h = t & 1;
  int v = b * BSIZE + n;
  if (v < N_NODES) {
    float inv = 1.0f / fmaxf((float)dcnt[n], 1.0f);
    const float* ap = &acc[n * AP1 + 16 * h];
    unsigned w0 = f2bf(ap[0] * inv)  | (f2bf(ap[1] * inv) << 16);
    unsigned w1 = f2bf(ap[2] * inv)  | (f2bf(ap[3] * inv) << 16);
    unsigned w2 = f2bf(ap[4] * inv)  | (f2bf(ap[5] * inv) << 16);
    unsigned w3 = f2bf(ap[6] * inv)  | (f2bf(ap[7] * inv) << 16);
    unsigned w4 = f2bf(ap[8] * inv)  | (f2bf(ap[9] * inv) << 16);
    unsigned w5 = f2bf(ap[10] * inv) | (f2bf(ap[11] * inv) << 16);
    unsigned w6 = f2bf(ap[12] * inv) | (f2bf(ap[13] * inv) << 16);
    unsigned w7 = f2bf(ap[14] * inv) | (f2bf(ap[15] * inv) << 16);
    meanb[v * 4 + 2 * h]     = make_uint4(w0, w1, w2, w3);
    meanb[v * 4 + 2 * h + 1] = make_uint4(w4, w5, w6, w7);
  }
}

// ------- l1g: DENSE loads only (self-feat fp32 + meanb bf16) + the R9-verified
//         two-pass register-tiled GEMM. No gather, no col/cnt. LDS 25.4 KB. -------
__global__ __launch_bounds__(256) void l1g_kernel(
    const float* __restrict__ feat, const uint4* __restrict__ meanb,
    const float* __restrict__ W1s, const float* __restrict__ W1n,
    const float* __restrict__ b1,
    const float* __restrict__ W2n, const float* __restrict__ W2s,
    unsigned* __restrict__ t2f8, float* __restrict__ s2) {
  __shared__ float sA[64 * APITCH];   // A^T: rows 0..31 self-feat, 32..63 mean-feat; 17.4 KB
  __shared__ float sW[64 * 32];       // 8 KB: W1cat col-half (phase 1 A/B), W2cat (phase 2)

  int t = threadIdx.x;
  int tile = blockIdx.x * 64;
  int nvalid = min(64, N_NODES - tile);

  // ---- issue all loads up front ----
  const float4* Fg = (const float4*)(feat + (size_t)tile * IN_F);
  int lim = nvalid * 8;
  int fi0 = t, fi1 = t + 256;
  float4 fa0, fa1;
  if (fi0 < lim) fa0 = Fg[fi0];
  if (fi1 < lim) fa1 = Fg[fi1];
  int wrow = t >> 3, wq = t & 7;
  const float4* srcw0 = (wrow < 32) ? (const float4*)W1s : (const float4*)W1n;
  int wrow1 = (t + 256) >> 3, wq1 = (t + 256) & 7;
  const float4* srcw1 = (wrow1 < 32) ? (const float4*)W1s : (const float4*)W1n;
  float4 wa0 = srcw0[(wrow & 31) * 16 + wq];     // cols 0..31
  float4 wa1 = srcw1[(wrow1 & 31) * 16 + wq1];

  // ---- dense mean-features: 4 threads/node, one uint4 (8 bf16) each ----
  {
    int nl = t >> 2, q = t & 3;
    int v = tile + nl;
    if (nl < nvalid) {
      uint4 mb = meanb[v * 4 + q];
      int j0 = 8 * q;
      sA[(32 + j0 + 0) * APITCH + nl] = __uint_as_float(mb.x << 16);
      sA[(32 + j0 + 1) * APITCH + nl] = __uint_as_float(mb.x & 0xFFFF0000u);
      sA[(32 + j0 + 2) * APITCH + nl] = __uint_as_float(mb.y << 16);
      sA[(32 + j0 + 3) * APITCH + nl] = __uint_as_float(mb.y & 0xFFFF0000u);
      sA[(32 + j0 + 4) * APITCH + nl] = __uint_as_float(mb.z << 16);
      sA[(32 + j0 + 5) * APITCH + nl] = __uint_as_float(mb.z & 0xFFFF0000u);
      sA[(32 + j0 + 6) * APITCH + nl] = __uint_as_float(mb.w << 16);
      sA[(32 + j0 + 7) * APITCH + nl] = __uint_as_float(mb.w & 0xFFFF0000u);
    }
  }

  // ---- self-feat + W1-A to LDS ----
  if (fi0 < lim) {
    int n = fi0 >> 3, c8 = fi0 & 7;
    sA[(4 * c8 + 0) * APITCH + n] = fa0.x;
    sA[(4 * c8 + 1) * APITCH + n] = fa0.y;
    sA[(4 * c8 + 2) * APITCH + n] = fa0.z;
    sA[(4 * c8 + 3) * APITCH + n] = fa0.w;
  }
  if (fi1 < lim) {
    int n = fi1 >> 3, c8 = fi1 & 7;
    sA[(4 * c8 + 0) * APITCH + n] = fa1.x;
    sA[(4 * c8 + 1) * APITCH + n] = fa1.y;
    sA[(4 * c8 + 2) * APITCH + n] = fa1.z;
    sA[(4 * c8 + 3) * APITCH + n] = fa1.w;
  }
  {
    float4* Ws = (float4*)sW;
    Ws[t] = wa0;                        // stage W1 cols 0..31
    Ws[t + 256] = wa1;
  }
  // ---- issue W1 col-half B: hides under pass A's FMA loop ----
  float4 wb0 = srcw0[(wrow & 31) * 16 + 8 + wq];
  float4 wb1 = srcw1[(wrow1 & 31) * 16 + 8 + wq1];

  int tx = t & 15, ty = t >> 4;
  int n0 = 4 * ty, cA = 2 * tx;
  float2 bbA = ((const float2*)b1)[tx];
  float2 bbB = ((const float2*)b1)[16 + tx];
  __syncthreads();                      // (1) sA + sW-A ready

  // ---- phase 1, pass A: cols 0..31 ----
  float aA[4][2], aB[4][2];
#pragma unroll
  for (int i = 0; i < 4; ++i) {
    aA[i][0] = bbA.x; aA[i][1] = bbA.y;
    aB[i][0] = bbB.x; aB[i][1] = bbB.y;
  }
#pragma unroll 4
  for (int k = 0; k < 64; ++k) {
    float4 a = *(const float4*)&sA[k * APITCH + n0];
    float2 w = *(const float2*)&sW[k * 32 + cA];
    aA[0][0] += a.x * w.x; aA[0][1] += a.x * w.y;
    aA[1][0] += a.y * w.x; aA[1][1] += a.y * w.y;
    aA[2][0] += a.z * w.x; aA[2][1] += a.z * w.y;
    aA[3][0] += a.w * w.x; aA[3][1] += a.w * w.y;
  }
  __syncthreads();                      // (2) pass A reads of sW done
  {
    float4* Ws = (float4*)sW;
    Ws[t] = wb0;                        // stage W1 cols 32..63
    Ws[t + 256] = wb1;
  }
  __syncthreads();                      // (3) sW-B ready

  // ---- phase 1, pass B: cols 32..63 ----
#pragma unroll 4
  for (int k = 0; k < 64; ++k) {
    float4 a = *(const float4*)&sA[k * APITCH + n0];
    float2 w = *(const float2*)&sW[k * 32 + cA];
    aB[0][0] += a.x * w.x; aB[0][1] += a.x * w.y;
    aB[1][0] += a.y * w.x; aB[1][1] += a.y * w.y;
    aB[2][0] += a.z * w.x; aB[2][1] += a.z * w.y;
    aB[3][0] += a.w * w.x; aB[3][1] += a.w * w.y;
  }
  __syncthreads();                      // (4) all phase-1 reads of sA done

  // ---- write h1^T (relu) back into sA; restage W2cat into sW ----
#pragma unroll
  for (int j = 0; j < 2; ++j) {
    float4 v;
    v.x = fmaxf(aA[0][j], 0.0f);
    v.y = fmaxf(aA[1][j], 0.0f);
    v.z = fmaxf(aA[2][j], 0.0f);
    v.w = fmaxf(aA[3][j], 0.0f);
    *(float4*)&sA[(cA + j) * APITCH + n0] = v;
    float4 u;
    u.x = fmaxf(aB[0][j], 0.0f);
    u.y = fmaxf(aB[1][j], 0.0f);
    u.z = fmaxf(aB[2][j], 0.0f);
    u.w = fmaxf(aB[3][j], 0.0f);
    *(float4*)&sA[(32 + cA + j) * APITCH + n0] = u;
  }
  {
    float4* Ws = (float4*)sW;
#pragma unroll
    for (int it = 0; it < 2; ++it) {
      int idx = t + 256 * it;
      int row = idx >> 3, ch = idx & 7;
      const float4* srcw = (ch < 4) ? (const float4*)W2n : (const float4*)W2s;
      Ws[row * 8 + ch] = srcw[row * 4 + (ch & 3)];
    }
  }
  __syncthreads();                      // (5) h1^T + W2cat ready

  // ---- phase 2: 4 nodes x 2 cols per thread; t2 stored as fp8 pairs ----
  int c2 = cA;
  float a0 = 0.f, a1 = 0.f, b0 = 0.f, b1_ = 0.f, d0 = 0.f, d1 = 0.f, e0 = 0.f, e1 = 0.f;
#pragma unroll 4
  for (int k = 0; k < 64; ++k) {
    float4 a = *(const float4*)&sA[k * APITCH + n0];
    float2 w = *(const float2*)&sW[k * 32 + c2];
    a0 += a.x * w.x; a1 += a.x * w.y;
    b0 += a.y * w.x; b1_ += a.y * w.y;
    d0 += a.z * w.x; d1 += a.z * w.y;
    e0 += a.w * w.x; e1 += a.w * w.y;
  }
  {
    float rs[4][2] = {{a0, a1}, {b0, b1_}, {d0, d1}, {e0, e1}};
    int cc = c2 & 15;
#pragma unroll
    for (int i = 0; i < 4; ++i) {
      int v = tile + n0 + i;
      if (v < N_NODES) {
        if (c2 < 16) {
          int w = __builtin_amdgcn_cvt_pk_fp8_f32(rs[i][0], rs[i][1], 0, false);
          *(unsigned short*)((char*)t2f8 + (size_t)v * 16 + cc) = (unsigned short)w;
        } else {
          *(float2*)&s2[v * OUT_F + cc] = make_float2(rs[i][0], rs[i][1]);
        }
      }
    }
  }
}

// ---- layer-2 aggregation + final, EDGE-PARALLEL: same pattern as agg1 but 16
//      floats/edge from t2f8; epilogue adds s2 + b2 and writes out dense. ----
__global__ __launch_bounds__(1024) void agg2_kernel(
    const unsigned* __restrict__ sorted, const int* __restrict__ cursor,
    const uint4* __restrict__ t2f8, const float* __restrict__ s2,
    const float* __restrict__ b2, float* __restrict__ out) {
  __shared__ float acc[BSIZE * AP2];   // 512*17*4 = 34.8 KB
  __shared__ int dcnt[BSIZE];
  int t = threadIdx.x;
  int b = blockIdx.x;
  for (int i = t; i < BSIZE * AP2; i += 1024) acc[i] = 0.0f;
  if (t < BSIZE) dcnt[t] = 0;
  __syncthreads();

  int cbase = b * CAP;
  int ne = cursor[b] - cbase;
  for (int i = t; i < ne; i += 1024) {
    unsigned p = sorted[cbase + i];       // coalesced
    int d = (int)(p & (BSIZE - 1));
    int sv = (int)(p >> 9);
    uint4 q = t2f8[sv];
    atomicAdd(&dcnt[d], 1);
    float* ap = &acc[d * AP2];
    ADDQL(ap, q, 0);
  }
  __syncthreads();

  // ---- epilogue: 2 threads/node; out = s2 + b2 + acc/deg, dense ----
  int n = t >> 1, h = t & 1;
  int v = b * BSIZE + n;
  if (v < N_NODES) {
    float inv = 1.0f / fmaxf((float)dcnt[n], 1.0f);
    const float* ap = &acc[n * AP2 + 8 * h];
    const float4* S = (const float4*)s2;
    const float4* B = (const float4*)b2;
    float4* O = (float4*)out;
#pragma unroll
    for (int i = 0; i < 2; ++i) {
      int ii = 2 * h + i;
      float4 sv = S[v * 4 + ii];
      float4 bv = B[ii];
      float4 r;
      r.x = sv.x + bv.x + ap[4 * i + 0] * inv;
      r.y = sv.y + bv.y + ap[4 * i + 1] * inv;
      r.z = sv.z + bv.z + ap[4 * i + 2] * inv;
      r.w = sv.w + bv.w + ap[4 * i + 3] * inv;
      O[v * 4 + ii] = r;
    }
  }
}

extern "C" void kernel_launch(void* const* d_in, const int* in_sizes, int n_in,
                              void* d_out, int out_size, void* d_ws, size_t ws_size,
                              hipStream_t stream) {
  const float* feat = (const float*)d_in[0];
  const int* src    = (const int*)d_in[1];
  const int* dst    = (const int*)d_in[2];
  const float* W1s  = (const float*)d_in[3];
  const float* W1n  = (const float*)d_in[4];
  const float* b1   = (const float*)d_in[5];
  const float* W2s  = (const float*)d_in[6];
  const float* W2n  = (const float*)d_in[7];
  const float* b2   = (const float*)d_in[8];
  float* out = (float*)d_out;

  const size_t N = N_NODES;
  const size_t SLAB = (size_t)NBUCK * CAP;        // 2,007,040 entries (8.03 MB)
  // workspace layout (~25.7 MB; col arena eliminated)
  unsigned* sorted = (unsigned*)d_ws;             // SLAB uint32 (8.03 MB) — live through agg2
  unsigned* featfp8 = sorted + SLAB + 16;         // 8N uints (3.2 MB)
  unsigned* meanb = featfp8 + 8 * N + 16;         // 16N uints as uint4 (6.4 MB, bf16 means)
  unsigned* t2f8 = meanb + 16 * N + 16;           // 4N uints (1.6 MB)
  float* s2 = (float*)(t2f8 + 4 * N + 16);        // 16N fp32 (6.4 MB)
  int* cursor = (int*)(s2 + 16 * N + 16);         // NBKT ints

  cursor_init_kernel<<<1, NBKT, 0, stream>>>(cursor);
  bucket_kernel<<<NCHUNK, 512, 0, stream>>>(
      src, dst, (const float4*)feat, (uint4*)featfp8, cursor, sorted);
  agg1_kernel<<<NBUCK, 1024, 0, stream>>>(
      sorted, cursor, (const uint4*)featfp8, (uint4*)meanb);
  l1g_kernel<<<(N_NODES + 63) / 64, 256, 0, stream>>>(
      feat, (const uint4*)meanb, W1s, W1n, b1, W2n, W2s, t2f8, s2);
  agg2_kernel<<<NBUCK, 1024, 0, stream>>>(
      sorted, cursor, (const uint4*)t2f8, s2, b2, out);
}

// Round 11
// 164.617 us; speedup vs baseline: 3.9103x; 3.9103x over previous
//
#include <hip/hip_runtime.h>

#define N_NODES 100000
#define N_EDGES 1600000
#define IN_F 32
#define HID_F 64
#define OUT_F 16
#define BSIZE 512                    // nodes per bucket (bucket = dst >> 9)
#define NBKT 256                     // scan width in bucket_kernel (196 used)
#define CHUNK 4096                   // edges per block in bucket-sort pass (391 blocks)
#define NBUCK ((N_NODES + BSIZE - 1) / BSIZE)   // 196
#define NCHUNK ((N_EDGES + CHUNK - 1) / CHUNK)  // 391
#define CAPN 48                      // per-node arena capacity (Poisson(16); P(deg>=48)~1e-9/node)
#define APITCH 68                    // padded pitch for transposed A / h1 tiles

using f2v = __attribute__((ext_vector_type(2))) float;

// accumulate 16 fp8-e4m3 (packed in uint4 Q, HW decode) into 16 fp32 accumulators
#define ADDQ(s, Q) do { f2v p_; \
  p_ = __builtin_amdgcn_cvt_pk_f32_fp8((int)(Q).x, false); s[0] += p_[0]; s[1] += p_[1]; \
  p_ = __builtin_amdgcn_cvt_pk_f32_fp8((int)(Q).x, true);  s[2] += p_[0]; s[3] += p_[1]; \
  p_ = __builtin_amdgcn_cvt_pk_f32_fp8((int)(Q).y, false); s[4] += p_[0]; s[5] += p_[1]; \
  p_ = __builtin_amdgcn_cvt_pk_f32_fp8((int)(Q).y, true);  s[6] += p_[0]; s[7] += p_[1]; \
  p_ = __builtin_amdgcn_cvt_pk_f32_fp8((int)(Q).z, false); s[8] += p_[0]; s[9] += p_[1]; \
  p_ = __builtin_amdgcn_cvt_pk_f32_fp8((int)(Q).z, true);  s[10] += p_[0]; s[11] += p_[1]; \
  p_ = __builtin_amdgcn_cvt_pk_f32_fp8((int)(Q).w, false); s[12] += p_[0]; s[13] += p_[1]; \
  p_ = __builtin_amdgcn_cvt_pk_f32_fp8((int)(Q).w, true);  s[14] += p_[0]; s[15] += p_[1]; \
} while (0)

// ---- one-pass LDS bucket-group, CHUNK-LOCAL output: each block writes its own
//      sorted[c*CHUNK ..] region coalesced (single writer — no cross-XCD line sharing,
//      no cursor atomics) + inclusive histogram hist[c][b]. Absorbs feat->fp8 conv. ----
__global__ __launch_bounds__(512) void bucket_kernel(
    const int* __restrict__ src, const int* __restrict__ dst,
    const float4* __restrict__ featin, uint4* __restrict__ featfp8,
    unsigned* __restrict__ sorted, int* __restrict__ hist) {
  __shared__ unsigned stage[CHUNK];        // 16 KB
  __shared__ int lcnt[NBKT], lscan[NBKT];
  __shared__ int wsum[4];
  int t = threadIdx.x;

  // ---- absorbed conversion: feat -> fp8 e4m3 (16 floats per thread, independent work) ----
  {
    int gtid = blockIdx.x * 512 + t;       // 391*512 = 200192 >= 200000
    if (gtid < N_NODES * IN_F / 16) {
      float4 a = featin[4 * gtid], bb = featin[4 * gtid + 1];
      float4 c4 = featin[4 * gtid + 2], d = featin[4 * gtid + 3];
      uint4 r;
      int w;
      w = __builtin_amdgcn_cvt_pk_fp8_f32(a.x, a.y, 0, false);
      w = __builtin_amdgcn_cvt_pk_fp8_f32(a.z, a.w, w, true);
      r.x = (unsigned)w;
      w = __builtin_amdgcn_cvt_pk_fp8_f32(bb.x, bb.y, 0, false);
      w = __builtin_amdgcn_cvt_pk_fp8_f32(bb.z, bb.w, w, true);
      r.y = (unsigned)w;
      w = __builtin_amdgcn_cvt_pk_fp8_f32(c4.x, c4.y, 0, false);
      w = __builtin_amdgcn_cvt_pk_fp8_f32(c4.z, c4.w, w, true);
      r.z = (unsigned)w;
      w = __builtin_amdgcn_cvt_pk_fp8_f32(d.x, d.y, 0, false);
      w = __builtin_amdgcn_cvt_pk_fp8_f32(d.z, d.w, w, true);
      r.w = (unsigned)w;
      featfp8[gtid] = r;
    }
  }

  if (t < NBKT) lcnt[t] = 0;
  __syncthreads();

  int base = blockIdx.x * CHUNK;
  unsigned mypk[CHUNK / 512];
  int myb[CHUNK / 512], myrank[CHUNK / 512];
#pragma unroll
  for (int i = 0; i < CHUNK / 512; ++i) {
    int e = base + t + 512 * i;
    if (e < N_EDGES) {
      unsigned s = (unsigned)src[e], d = (unsigned)dst[e];
      myb[i] = (int)(d >> 9);
      mypk[i] = (s << 9) | (d & 511u);
      myrank[i] = atomicAdd(&lcnt[myb[i]], 1);
    } else {
      myb[i] = -1;
    }
  }
  __syncthreads();

  // ---- inclusive scan of lcnt[0..255] via wave shfl (threads 0..255 = waves 0..3) ----
  int x = 0;
  if (t < NBKT) {
    x = lcnt[t];
#pragma unroll
    for (int off = 1; off < 64; off <<= 1) {
      int y = __shfl_up(x, off);
      if ((t & 63) >= off) x += y;
    }
    if ((t & 63) == 63) wsum[t >> 6] = x;
  }
  __syncthreads();
  if (t < NBKT) {
    int w = t >> 6, add = 0;
    if (w > 0) add += wsum[0];
    if (w > 1) add += wsum[1];
    if (w > 2) add += wsum[2];
    int incl = x + add;
    lscan[t] = incl;
    hist[blockIdx.x * NBKT + t] = incl;   // inclusive local histogram
  }
  __syncthreads();

#pragma unroll
  for (int i = 0; i < CHUNK / 512; ++i) {
    if (myb[i] >= 0) {
      int slot = (lscan[myb[i]] - lcnt[myb[i]]) + myrank[i];
      stage[slot] = mypk[i];
    }
  }
  __syncthreads();
  int nvalid = min(CHUNK, N_EDGES - base);
  for (int i = t; i < nvalid; i += 512)
    sorted[base + i] = stage[i];           // coalesced, own region only
}

// ---- scan-free arena CSR v2: one block per bucket; 2 threads per chunk walk the
//      contiguous bucket-b span of that chunk (reads only — no shared-line writes);
//      LDS atomic ranks -> single-writer col window (the verified locality rule). ----
__global__ __launch_bounds__(1024) void csr_kernel(
    const unsigned* __restrict__ sorted, const int* __restrict__ hist,
    int* __restrict__ cnt, int* __restrict__ col) {
  __shared__ int dcnt[BSIZE];
  int t = threadIdx.x;
  int b = blockIdx.x;
  if (t < BSIZE) dcnt[t] = 0;
  __syncthreads();

  if (t < 2 * NCHUNK) {
    int c = t >> 1, h = t & 1;
    int s0 = b ? hist[c * NBKT + b - 1] : 0;
    int e0 = hist[c * NBKT + b];
    int cb = c * CHUNK;
    for (int i = s0 + h; i < e0; i += 2) {
      unsigned p = sorted[cb + i];
      int d = (int)(p & (BSIZE - 1));
      int r = atomicAdd(&dcnt[d], 1);
      if (r < CAPN) col[(b * BSIZE + d) * CAPN + r] = (int)(p >> 9);
    }
  }
  __syncthreads();
  if (t < BSIZE) {
    int v = b * BSIZE + t;
    if (v < N_NODES) cnt[v] = dcnt[t];   // true in-degree (mean divisor)
  }
}

// ------- fused: per-tile fp8 gather (mean-feat -> LDS) + register-tiled GEMM.
//         (byte-identical to R9: LDS 25.6 KB, two-pass phase 1, no min-wave bound) -------
__global__ __launch_bounds__(256) void l1g_kernel(
    const float* __restrict__ feat, const uint4* __restrict__ featfp8,
    const int* __restrict__ cnt, const int* __restrict__ col,
    const float* __restrict__ W1s, const float* __restrict__ W1n,
    const float* __restrict__ b1,
    const float* __restrict__ W2n, const float* __restrict__ W2s,
    unsigned* __restrict__ t2f8, float* __restrict__ s2) {
  __shared__ float sA[64 * APITCH];   // A^T: rows 0..31 self-feat, 32..63 mean-feat; 17.4 KB
  __shared__ float sW[64 * 32];       // 8 KB: W1cat col-half (phase 1 A/B), W2cat (phase 2)

  int t = threadIdx.x;
  int tile = blockIdx.x * 64;
  int nvalid = min(64, N_NODES - tile);

  // ---- register staging: issue self-feat + W1 col-half A NOW, write to LDS later ----
  const float4* Fg = (const float4*)(feat + (size_t)tile * IN_F);
  int lim = nvalid * 8;
  int fi0 = t, fi1 = t + 256;
  float4 fa0, fa1;
  if (fi0 < lim) fa0 = Fg[fi0];
  if (fi1 < lim) fa1 = Fg[fi1];
  int wrow = t >> 3, wq = t & 7;                 // thread -> (row, quad) for W1 staging
  const float4* srcw0 = (wrow < 32) ? (const float4*)W1s : (const float4*)W1n;
  int wrow1 = (t + 256) >> 3, wq1 = (t + 256) & 7;
  const float4* srcw1 = (wrow1 < 32) ? (const float4*)W1s : (const float4*)W1n;
  float4 wa0 = srcw0[(wrow & 31) * 16 + wq];     // cols 0..31
  float4 wa1 = srcw1[(wrow1 & 31) * 16 + wq1];

  // ---- gather mean-features: 4 lanes/node (half edges each), int4 col + fp8 16B loads ----
  {
    int nl = t >> 2, c = (t >> 1) & 1, hp = t & 1;
    int v = tile + nl;
    if (nl < nvalid) {
      int deg = cnt[v];
      int start = v * CAPN;
      int dclamp = min(deg, CAPN);
      int end = start + dclamp;
      float s[16];
#pragma unroll
      for (int j = 0; j < 16; ++j) s[j] = 0.0f;
      int nf = dclamp & ~7;
      for (int g = 0; g < nf; g += 8) {
        int4 cc = *(const int4*)&col[start + g + 4 * hp];
        uint4 q0 = featfp8[cc.x * 2 + c];
        uint4 q1 = featfp8[cc.y * 2 + c];
        uint4 q2 = featfp8[cc.z * 2 + c];
        uint4 q3 = featfp8[cc.w * 2 + c];
        ADDQ(s, q0);
        ADDQ(s, q1);
        ADDQ(s, q2);
        ADDQ(s, q3);
      }
      for (int e = start + nf + hp; e < end; e += 2) {
        uint4 q = featfp8[col[e] * 2 + c];
        ADDQ(s, q);
      }
      // pair-reduce edge halves (partner = t^1, same wave)
#pragma unroll
      for (int j = 0; j < 16; ++j) s[j] += __shfl_xor(s[j], 1);
      float inv = 1.0f / fmaxf((float)deg, 1.0f);
      int j0 = 8 * hp;                 // split the 16 LDS writes across the pair
#pragma unroll
      for (int j = 0; j < 8; ++j)
        sA[(32 + 16 * c + j0 + j) * APITCH + nl] = s[j0 + j] * inv;   // meanf^T
    }
  }

  // ---- write staged registers to LDS (loads completed under the gather) ----
  if (fi0 < lim) {
    int n = fi0 >> 3, c8 = fi0 & 7;
    sA[(4 * c8 + 0) * APITCH + n] = fa0.x;
    sA[(4 * c8 + 1) * APITCH + n] = fa0.y;
    sA[(4 * c8 + 2) * APITCH + n] = fa0.z;
    sA[(4 * c8 + 3) * APITCH + n] = fa0.w;
  }
  if (fi1 < lim) {
    int n = fi1 >> 3, c8 = fi1 & 7;
    sA[(4 * c8 + 0) * APITCH + n] = fa1.x;
    sA[(4 * c8 + 1) * APITCH + n] = fa1.y;
    sA[(4 * c8 + 2) * APITCH + n] = fa1.z;
    sA[(4 * c8 + 3) * APITCH + n] = fa1.w;
  }
  {
    float4* Ws = (float4*)sW;
    Ws[t] = wa0;                        // stage W1 cols 0..31
    Ws[t + 256] = wa1;
  }
  // ---- issue W1 col-half B now: latency hides under pass A's 64-iter FMA loop ----
  float4 wb0 = srcw0[(wrow & 31) * 16 + 8 + wq];   // cols 32..63
  float4 wb1 = srcw1[(wrow1 & 31) * 16 + 8 + wq1];

  int tx = t & 15, ty = t >> 4;
  int n0 = 4 * ty, cA = 2 * tx;        // thread owns cols {cA,cA+1} and {32+cA,33+cA}
  float2 bbA = ((const float2*)b1)[tx];
  float2 bbB = ((const float2*)b1)[16 + tx];
  __syncthreads();                      // (1) sA + sW-A ready

  // ---- phase 1, pass A: cols 0..31 ----
  float aA[4][2], aB[4][2];
#pragma unroll
  for (int i = 0; i < 4; ++i) {
    aA[i][0] = bbA.x; aA[i][1] = bbA.y;
    aB[i][0] = bbB.x; aB[i][1] = bbB.y;
  }
#pragma unroll 4
  for (int k = 0; k < 64; ++k) {
    float4 a = *(const float4*)&sA[k * APITCH + n0];
    float2 w = *(const float2*)&sW[k * 32 + cA];
    aA[0][0] += a.x * w.x; aA[0][1] += a.x * w.y;
    aA[1][0] += a.y * w.x; aA[1][1] += a.y * w.y;
    aA[2][0] += a.z * w.x; aA[2][1] += a.z * w.y;
    aA[3][0] += a.w * w.x; aA[3][1] += a.w * w.y;
  }
  __syncthreads();                      // (2) pass A reads of sW done
  {
    float4* Ws = (float4*)sW;
    Ws[t] = wb0;                        // stage W1 cols 32..63
    Ws[t + 256] = wb1;
  }
  __syncthreads();                      // (3) sW-B ready

  // ---- phase 1, pass B: cols 32..63 ----
#pragma unroll 4
  for (int k = 0; k < 64; ++k) {
    float4 a = *(const float4*)&sA[k * APITCH + n0];
    float2 w = *(const float2*)&sW[k * 32 + cA];
    aB[0][0] += a.x * w.x; aB[0][1] += a.x * w.y;
    aB[1][0] += a.y * w.x; aB[1][1] += a.y * w.y;
    aB[2][0] += a.z * w.x; aB[2][1] += a.z * w.y;
    aB[3][0] += a.w * w.x; aB[3][1] += a.w * w.y;
  }
  __syncthreads();                      // (4) all phase-1 reads of sA done

  // ---- write h1^T (relu) back into sA; restage W2cat into sW ----
#pragma unroll
  for (int j = 0; j < 2; ++j) {
    float4 v;
    v.x = fmaxf(aA[0][j], 0.0f);
    v.y = fmaxf(aA[1][j], 0.0f);
    v.z = fmaxf(aA[2][j], 0.0f);
    v.w = fmaxf(aA[3][j], 0.0f);
    *(float4*)&sA[(cA + j) * APITCH + n0] = v;
    float4 u;
    u.x = fmaxf(aB[0][j], 0.0f);
    u.y = fmaxf(aB[1][j], 0.0f);
    u.z = fmaxf(aB[2][j], 0.0f);
    u.w = fmaxf(aB[3][j], 0.0f);
    *(float4*)&sA[(32 + cA + j) * APITCH + n0] = u;
  }
  {
    float4* Ws = (float4*)sW;
#pragma unroll
    for (int it = 0; it < 2; ++it) {
      int idx = t + 256 * it;
      int row = idx >> 3, ch = idx & 7;
      const float4* srcw = (ch < 4) ? (const float4*)W2n : (const float4*)W2s;
      Ws[row * 8 + ch] = srcw[row * 4 + (ch & 3)];
    }
  }
  __syncthreads();                      // (5) h1^T + W2cat ready

  // ---- phase 2: 4 nodes x 2 cols per thread; t2 stored as fp8 pairs ----
  int c2 = cA;
  float a0 = 0.f, a1 = 0.f, b0 = 0.f, b1_ = 0.f, d0 = 0.f, d1 = 0.f, e0 = 0.f, e1 = 0.f;
#pragma unroll 4
  for (int k = 0; k < 64; ++k) {
    float4 a = *(const float4*)&sA[k * APITCH + n0];
    float2 w = *(const float2*)&sW[k * 32 + c2];
    a0 += a.x * w.x; a1 += a.x * w.y;
    b0 += a.y * w.x; b1_ += a.y * w.y;
    d0 += a.z * w.x; d1 += a.z * w.y;
    e0 += a.w * w.x; e1 += a.w * w.y;
  }
  {
    float rs[4][2] = {{a0, a1}, {b0, b1_}, {d0, d1}, {e0, e1}};
    int cc = c2 & 15;
#pragma unroll
    for (int i = 0; i < 4; ++i) {
      int v = tile + n0 + i;
      if (v < N_NODES) {
        if (c2 < 16) {
          int w = __builtin_amdgcn_cvt_pk_fp8_f32(rs[i][0], rs[i][1], 0, false);
          *(unsigned short*)((char*)t2f8 + (size_t)v * 16 + cc) = (unsigned short)w;
        } else {
          *(float2*)&s2[v * OUT_F + cc] = make_float2(rs[i][0], rs[i][1]);
        }
      }
    }
  }
}

// ------- layer 2 aggregate + final: fp8 gather, 4 lanes/node, int4 col (R9-verbatim) -------
__global__ __launch_bounds__(256) void gather2_final_kernel(
    const int* __restrict__ cnt, const int* __restrict__ col,
    const uint4* __restrict__ t2f8, const float* __restrict__ s2,
    const float* __restrict__ b2, float* __restrict__ out) {
  int g = blockIdx.x * 256 + threadIdx.x;
  int v = g >> 2, hp = g & 3;
  if (v >= N_NODES) return;
  int deg = cnt[v];
  int start = v * CAPN;
  int dclamp = min(deg, CAPN);
  int end = start + dclamp;
  float s[16];
#pragma unroll
  for (int j = 0; j < 16; ++j) s[j] = 0.0f;
  int nf = dclamp & ~15;               // 16-edge batches: one int4 per lane
  for (int gg = 0; gg < nf; gg += 16) {
    int4 cc = *(const int4*)&col[start + gg + 4 * hp];
    uint4 q0 = t2f8[cc.x];
    uint4 q1 = t2f8[cc.y];
    uint4 q2 = t2f8[cc.z];
    uint4 q3 = t2f8[cc.w];
    ADDQ(s, q0);
    ADDQ(s, q1);
    ADDQ(s, q2);
    ADDQ(s, q3);
  }
  int e0 = start + nf;
  if (dclamp - nf >= 8) {              // 8-edge mid-batch: one int2 per lane
    int2 cc = *(const int2*)&col[e0 + 2 * hp];
    uint4 q0 = t2f8[cc.x];
    uint4 q1 = t2f8[cc.y];
    ADDQ(s, q0);
    ADDQ(s, q1);
    e0 += 8;
  }
  for (int e = e0 + hp; e < end; e += 4) {
    uint4 q = t2f8[col[e]];
    ADDQ(s, q);
  }
  // reduce across the 4 lanes of this node (g = 4v+hp, same wave)
#pragma unroll
  for (int j = 0; j < 16; ++j) s[j] += __shfl_xor(s[j], 1);
#pragma unroll
  for (int j = 0; j < 16; ++j) s[j] += __shfl_xor(s[j], 2);
  float inv = 1.0f / fmaxf((float)deg, 1.0f);
  // lane hp writes output row hp; branchless select of its quarter (no dynamic reg index)
  float q0 = (hp == 0) ? s[0]  : (hp == 1) ? s[4]  : (hp == 2) ? s[8]  : s[12];
  float q1 = (hp == 0) ? s[1]  : (hp == 1) ? s[5]  : (hp == 2) ? s[9]  : s[13];
  float q2 = (hp == 0) ? s[2]  : (hp == 1) ? s[6]  : (hp == 2) ? s[10] : s[14];
  float q3 = (hp == 0) ? s[3]  : (hp == 1) ? s[7]  : (hp == 2) ? s[11] : s[15];
  float4 sv = ((const float4*)s2)[v * 4 + hp];
  float4 bv = ((const float4*)b2)[hp];
  float4 r;
  r.x = sv.x + bv.x + q0 * inv;
  r.y = sv.y + bv.y + q1 * inv;
  r.z = sv.z + bv.z + q2 * inv;
  r.w = sv.w + bv.w + q3 * inv;
  ((float4*)out)[v * 4 + hp] = r;
}

extern "C" void kernel_launch(void* const* d_in, const int* in_sizes, int n_in,
                              void* d_out, int out_size, void* d_ws, size_t ws_size,
                              hipStream_t stream) {
  const float* feat = (const float*)d_in[0];
  const int* src    = (const int*)d_in[1];
  const int* dst    = (const int*)d_in[2];
  const float* W1s  = (const float*)d_in[3];
  const float* W1n  = (const float*)d_in[4];
  const float* b1   = (const float*)d_in[5];
  const float* W2s  = (const float*)d_in[6];
  const float* W2n  = (const float*)d_in[7];
  const float* b2   = (const float*)d_in[8];
  float* out = (float*)d_out;

  const size_t N = N_NODES;
  const size_t SSZ = (size_t)NCHUNK * CHUNK;      // 1,601,536 entries (6.4 MB)
  // workspace layout (~30 MB): s2 overlays sorted (sorted dead after csr_kernel)
  int* cnt = (int*)d_ws;                          // N ints (400 KB)
  int* col = cnt + N + 16;                        // N*CAPN ints (19.2 MB arena)
  unsigned* sorted = (unsigned*)(col + N * CAPN + 16);  // chunk-local sorted (6.4 MB)
  float* s2 = (float*)sorted;                     // 16N fp32 (6.4 MB) — union with sorted
  int* hist = (int*)(sorted + SSZ + 16);          // NCHUNK*NBKT ints (400 KB)
  unsigned* featfp8 = (unsigned*)(hist + NCHUNK * NBKT + 16);  // 8N uints (3.2 MB)
  unsigned* t2f8 = featfp8 + 8 * N;               // 4N uints (1.6 MB)

  bucket_kernel<<<NCHUNK, 512, 0, stream>>>(
      src, dst, (const float4*)feat, (uint4*)featfp8, sorted, hist);
  csr_kernel<<<NBUCK, 1024, 0, stream>>>(sorted, hist, cnt, col);
  l1g_kernel<<<(N_NODES + 63) / 64, 256, 0, stream>>>(
      feat, (const uint4*)featfp8, cnt, col, W1s, W1n, b1, W2n, W2s, t2f8, s2);
  gather2_final_kernel<<<(4 * N_NODES + 255) / 256, 256, 0, stream>>>(
      cnt, col, (const uint4*)t2f8, s2, b2, out);
}